// Round 8
// baseline (757.842 us; speedup 1.0000x reference)
//
#include <hip/hip_runtime.h>
#include <hip/hip_bf16.h>

// Problem constants (B=4, S=2048, D=1024, E=8, K=2, DFF=2048)
#define T_TOK 8192
#define D_DIM 1024
#define E_NUM 8
#define DFF_DIM 2048
#define MAX_PAIRS_PAD 17408   // 136 * 128 (128-granular per-expert padding)
#define MAX_TILES256 72       // sum_e ceil(padded128_e/256) <= 64 + 8

typedef __attribute__((ext_vector_type(8))) short short8_t;
typedef __attribute__((ext_vector_type(4))) float f32x4;

__device__ __forceinline__ unsigned short f2b(float f) {
  union { float f; unsigned u; } v; v.f = f;
  unsigned u = v.u;
  return (unsigned short)((u + 0x7fffu + ((u >> 16) & 1u)) >> 16);
}

__device__ __forceinline__ void gload_lds16(const void* g, void* l) {
  __builtin_amdgcn_global_load_lds(
      (const __attribute__((address_space(1))) unsigned int*)g,
      (__attribute__((address_space(3))) unsigned int*)l, 16, 0, 0);
}

// src[R][C] fp32 -> dst[C][R] bf16 (tiled transpose, coalesced both sides)
__global__ void tcvt_kernel(const float* __restrict__ src, unsigned short* __restrict__ dst,
                            int R, int C) {
  __shared__ float tile[32][33];
  int c0 = blockIdx.x * 32, r0 = blockIdx.y * 32;
  int tx = threadIdx.x, ty = threadIdx.y;  // 32x8
  #pragma unroll
  for (int i = 0; i < 32; i += 8)
    tile[ty + i][tx] = src[(size_t)(r0 + ty + i) * C + c0 + tx];
  __syncthreads();
  #pragma unroll
  for (int i = 0; i < 32; i += 8)
    dst[(size_t)(c0 + ty + i) * R + r0 + tx] = f2b(tile[tx][ty + i]);
}

// ---------------- router: logits, top-2, renorm; fused x->bf16; no hot atomics
__global__ void router_kernel(const float* __restrict__ x, const float* __restrict__ rw,
                              int* __restrict__ sel, float* __restrict__ selw,
                              unsigned short* __restrict__ xb) {
  int tok = (blockIdx.x * blockDim.x + threadIdx.x) >> 6;  // one wave per token
  int lane = threadIdx.x & 63;
  if (tok >= T_TOK) return;
  const float4* xr = (const float4*)(x + (size_t)tok * D_DIM);
  ushort4* xbr = (ushort4*)(xb + (size_t)tok * D_DIM);
  float acc[E_NUM];
  #pragma unroll
  for (int e = 0; e < E_NUM; ++e) acc[e] = 0.f;
  #pragma unroll
  for (int it = 0; it < 4; ++it) {
    int i = it * 64 + lane;      // float4 index, 0..255
    float4 v = xr[i];
    ushort4 o;
    o.x = f2b(v.x); o.y = f2b(v.y); o.z = f2b(v.z); o.w = f2b(v.w);
    xbr[i] = o;                  // fused bf16 conversion of x
    const float* w = rw + (size_t)i * 4 * E_NUM;
    #pragma unroll
    for (int e = 0; e < E_NUM; ++e) acc[e] += v.x * w[e];
    #pragma unroll
    for (int e = 0; e < E_NUM; ++e) acc[e] += v.y * w[E_NUM + e];
    #pragma unroll
    for (int e = 0; e < E_NUM; ++e) acc[e] += v.z * w[2 * E_NUM + e];
    #pragma unroll
    for (int e = 0; e < E_NUM; ++e) acc[e] += v.w * w[3 * E_NUM + e];
  }
  #pragma unroll
  for (int e = 0; e < E_NUM; ++e) {
    float v = acc[e];
    #pragma unroll
    for (int off = 32; off > 0; off >>= 1) v += __shfl_xor(v, off, 64);
    acc[e] = v;
  }
  if (lane == 0) {
    float mx = acc[0];
    #pragma unroll
    for (int e = 1; e < E_NUM; ++e) mx = fmaxf(mx, acc[e]);
    float p[E_NUM];
    #pragma unroll
    for (int e = 0; e < E_NUM; ++e) p[e] = __expf(acc[e] - mx);
    int i0 = 0;
    #pragma unroll
    for (int e = 1; e < E_NUM; ++e) if (p[e] > p[i0]) i0 = e;
    int i1 = (i0 == 0) ? 1 : 0;
    #pragma unroll
    for (int e = 0; e < E_NUM; ++e) if (e != i0 && p[e] > p[i1]) i1 = e;
    float w0 = p[i0], w1 = p[i1];
    float inv = 1.f / (w0 + w1);   // softmax denominator cancels in renorm
    sel[tok * 2] = i0; selw[tok * 2] = w0 * inv;
    sel[tok * 2 + 1] = i1; selw[tok * 2 + 1] = w1 * inv;
  }
}

// ---------------- counts: LDS-aggregated histogram ----------------
__global__ void count_kernel(const int* __restrict__ sel, int* __restrict__ counts) {
  __shared__ int lc[E_NUM];
  if (threadIdx.x < E_NUM) lc[threadIdx.x] = 0;
  __syncthreads();
  int t = blockIdx.x * blockDim.x + threadIdx.x;
  if (t < 2 * T_TOK) atomicAdd(&lc[sel[t]], 1);
  __syncthreads();
  if (threadIdx.x < E_NUM) atomicAdd(&counts[threadIdx.x], lc[threadIdx.x]);
}

// ---------------- plan: 128-padded offsets + 256-row tile table + item counts
__global__ void plan_kernel(const int* __restrict__ counts, int* __restrict__ tiles_e,
                            int* __restrict__ tiles_b, int* __restrict__ tiles_l,
                            int* __restrict__ pad_off, int* __restrict__ cursor,
                            int* __restrict__ nitems, int* __restrict__ ptok,
                            float* __restrict__ pgate, unsigned short* __restrict__ zrow) {
  if (threadIdx.x == 0) {
    int b = 0, t = 0;
    for (int e = 0; e < E_NUM; ++e) {
      pad_off[e] = b;
      int p128 = ((counts[e] + 127) >> 7) << 7;     // 128-granular padded rows
      int nt = (p128 + 255) >> 8;                   // 256-row tile windows
      for (int i = 0; i < nt; ++i) {
        tiles_e[t] = e; tiles_b[t] = b + i * 256; tiles_l[t] = b + p128; ++t;
      }
      b += p128;
    }
    nitems[0] = t * 8;                 // gemm1: tiles * (2048/256)
    nitems[1] = t * 8;                 // gemm2: tiles * (1024/256) * splitK2
    for (; t < MAX_TILES256; ++t) { tiles_e[t] = -1; tiles_b[t] = 0; tiles_l[t] = 0; }
  }
  for (int i = threadIdx.x; i < MAX_PAIRS_PAD; i += blockDim.x) { ptok[i] = -1; pgate[i] = 0.f; }
  for (int i = threadIdx.x; i < 1040; i += blockDim.x) zrow[i] = 0;
  if (threadIdx.x < E_NUM) cursor[threadIdx.x] = 0;
}

// ---------------- scatter: block-level range reservation ----------------
__global__ void scatter_kernel(const int* __restrict__ sel, const float* __restrict__ selw,
                               const int* __restrict__ pad_off, int* __restrict__ cursor,
                               int* __restrict__ ptok, float* __restrict__ pgate) {
  __shared__ int lc[E_NUM];
  __shared__ int lbase[E_NUM];
  if (threadIdx.x < E_NUM) lc[threadIdx.x] = 0;
  __syncthreads();
  int t = blockIdx.x * blockDim.x + threadIdx.x;  // one thread per token
  int e0 = sel[t * 2], e1 = sel[t * 2 + 1];
  int o0 = atomicAdd(&lc[e0], 1);
  int o1 = atomicAdd(&lc[e1], 1);
  __syncthreads();
  if (threadIdx.x < E_NUM) lbase[threadIdx.x] = atomicAdd(&cursor[threadIdx.x], lc[threadIdx.x]);
  __syncthreads();
  int s0 = pad_off[e0] + lbase[e0] + o0;
  ptok[s0] = t; pgate[s0] = selw[t * 2];
  int s1 = pad_off[e1] + lbase[e1] + o1;
  ptok[s1] = t; pgate[s1] = selw[t * 2 + 1];
}

// ===== persistent 256x256x64 grouped GEMM, 2-phase core (r7, 0-conflict) =====
// 256 blocks steal (tile, nblk[, khalf]) items off a global counter.
// MODE 0: h = gelu(x_gather @ w1_e); items = tiles*8 (N=2048/256), K=1024.
// MODE 1: out[tok] += gate*(h @ w2_e); items = tiles*4*2 (N=1024/256, splitK2),
//         each item does K-half 1024; partials merge via fp32 atomicAdd.
template <int MODE>
__global__ __launch_bounds__(512, 2) void gemm2p_kernel(
    const unsigned short* __restrict__ Ag, const unsigned short* __restrict__ Bg,
    const int* __restrict__ ptok, const float* __restrict__ pgate,
    const int* __restrict__ tiles_e, const int* __restrict__ tiles_b,
    const int* __restrict__ tiles_l, const unsigned short* __restrict__ zrow,
    int* __restrict__ nitems, void* __restrict__ outp) {
  extern __shared__ char smem[];   // A [2][256][64]bf16 @0 (64KB), B same @65536
  __shared__ int s_item;
  char* const AsB = smem;
  char* const BsB = smem + 65536;

  const int n_items = nitems[MODE];
  int* wcnt = nitems + 4 + MODE;

  const int tid = threadIdx.x;
  const int lane = tid & 63;
  const int wv = tid >> 6;
  const int wr = wv >> 2, wc = wv & 3;   // 2M x 4N waves; per-wave out 128x64
  const int lr = lane & 15;
  const int lq = lane >> 4;
  const int lsw = lr & 7;                // read-side swizzle key (== row&7)

  constexpr int NK = 16;                 // 1024 K per item in both modes

  while (true) {
    if (tid == 0) s_item = atomicAdd(wcnt, 1);
    __syncthreads();
    const int item = s_item;
    if (item >= n_items) return;

    // ---- decode item ----
    const int tileIdx = item >> 3;
    int n0, kbase;
    if (MODE == 0) { n0 = (item & 7) * 256; kbase = 0; }
    else           { n0 = (item & 3) * 256; kbase = ((item >> 2) & 1) * 1024; }
    const int e = tiles_e[tileIdx];
    const int tbase = tiles_b[tileIdx];
    const int tlim = tiles_l[tileIdx];

    // ---- per-item staging sources (global col chunk pre-swizzled; LDS linear)
    const unsigned short* asrc[2][2];
    const unsigned short* bsrc[2][2];
    int sdst[2][2];
    #pragma unroll
    for (int hh = 0; hh < 2; ++hh) {
      #pragma unroll
      for (int i = 0; i < 2; ++i) {
        const int c = i * 512 + tid;
        const int row = c >> 3, col8 = c & 7;
        const int r256 = hh * 128 + row;
        const int col8s = col8 ^ (r256 & 7);     // T2: inverse-swizzled source
        int slot = tbase + r256; if (slot > MAX_PAIRS_PAD - 1) slot = MAX_PAIRS_PAD - 1;
        if (MODE == 0) {
          const int tok = ptok[slot];
          asrc[hh][i] = (tok >= 0) ? (Ag + (size_t)tok * D_DIM + col8s * 8) : (zrow + col8s * 8);
          bsrc[hh][i] = Bg + (size_t)(e * DFF_DIM + n0 + r256) * D_DIM + col8s * 8;
        } else {
          asrc[hh][i] = Ag + (size_t)slot * DFF_DIM + kbase + col8s * 8;
          bsrc[hh][i] = Bg + (size_t)(n0 + r256) * (E_NUM * DFF_DIM) + e * DFF_DIM + kbase + col8s * 8;
        }
        sdst[hh][i] = r256 * 128 + col8 * 16;    // LDS dest stays linear
      }
    }

#define STAGE_ALL(kt) do { const int kb_ = (kt) * 64;                                        \
    char* dA_ = AsB + ((kt) & 1) * 32768; char* dB_ = BsB + ((kt) & 1) * 32768;              \
    gload_lds16(asrc[0][0] + kb_, dA_ + sdst[0][0]);                                         \
    gload_lds16(asrc[0][1] + kb_, dA_ + sdst[0][1]);                                         \
    gload_lds16(asrc[1][0] + kb_, dA_ + sdst[1][0]);                                         \
    gload_lds16(asrc[1][1] + kb_, dA_ + sdst[1][1]);                                         \
    gload_lds16(bsrc[0][0] + kb_, dB_ + sdst[0][0]);                                         \
    gload_lds16(bsrc[0][1] + kb_, dB_ + sdst[0][1]);                                         \
    gload_lds16(bsrc[1][0] + kb_, dB_ + sdst[1][0]);                                         \
    gload_lds16(bsrc[1][1] + kb_, dB_ + sdst[1][1]); } while (0)
#define READ_A(dst, mh) do { const char* Ad_ = AsB + dboff;                                  \
    _Pragma("unroll") for (int m4 = 0; m4 < 4; ++m4)                                         \
      _Pragma("unroll") for (int ks = 0; ks < 2; ++ks)                                       \
        dst[m4 * 2 + ks] = *(const short8_t*)(Ad_ +                                          \
            (wr * 128 + ((mh) * 4 + m4) * 16 + lr) * 128 +                                   \
            ((ks * 4 + lq) ^ lsw) * 16); } while (0)
#define READ_B(dst, nh) do { const char* Bd_ = BsB + dboff;                                  \
    _Pragma("unroll") for (int n2 = 0; n2 < 2; ++n2)                                         \
      _Pragma("unroll") for (int ks = 0; ks < 2; ++ks)                                       \
        dst[n2 * 2 + ks] = *(const short8_t*)(Bd_ +                                          \
            (wc * 64 + ((nh) * 2 + n2) * 16 + lr) * 128 +                                    \
            ((ks * 4 + lq) ^ lsw) * 16); } while (0)
#define MFMA_Q(af, mh, bf, nh) do {                                                          \
    _Pragma("unroll") for (int m4 = 0; m4 < 4; ++m4)                                         \
      _Pragma("unroll") for (int n2 = 0; n2 < 2; ++n2)                                       \
        _Pragma("unroll") for (int ks = 0; ks < 2; ++ks)                                     \
          acc[(mh) * 4 + m4][(nh) * 2 + n2] = __builtin_amdgcn_mfma_f32_16x16x32_bf16(       \
              af[m4 * 2 + ks], bf[n2 * 2 + ks], acc[(mh) * 4 + m4][(nh) * 2 + n2], 0, 0, 0); \
  } while (0)

    f32x4 acc[8][4];
    #pragma unroll
    for (int m = 0; m < 8; ++m)
      #pragma unroll
      for (int n = 0; n < 4; ++n) acc[m][n] = (f32x4){0.f, 0.f, 0.f, 0.f};

    // prologue: stage tile 0, drain, barrier
    STAGE_ALL(0);
    asm volatile("s_waitcnt vmcnt(0)" ::: "memory");
    asm volatile("s_barrier" ::: "memory");

    for (int k = 0; k < NK; ++k) {
      const int dboff = (k & 1) * 32768;
      if (k + 1 < NK) STAGE_ALL(k + 1);   // issued first: ~1 full iter before its wait
      {
        short8_t aF0[8], aF1[8], bFa[4], bFb[4];
        READ_A(aF0, 0); READ_B(bFa, 0);
        MFMA_Q(aF0, 0, bFa, 0);
        READ_B(bFb, 1);
        MFMA_Q(aF0, 0, bFb, 1);
        READ_A(aF1, 1);
        MFMA_Q(aF1, 1, bFb, 1);
        MFMA_Q(aF1, 1, bFa, 0);
      }
      asm volatile("s_waitcnt vmcnt(0)" ::: "memory");
      asm volatile("s_barrier" ::: "memory");
    }

    // ---- epilogue (regs only; LDS free for next item's stage) ----
    if (MODE == 0) {
      unsigned short* h = (unsigned short*)outp;
      #pragma unroll
      for (int m = 0; m < 8; ++m) {
        #pragma unroll
        for (int j = 0; j < 4; ++j) {
          const int grow = tbase + wr * 128 + m * 16 + lq * 4 + j;
          if (grow >= tlim) continue;
          #pragma unroll
          for (int n = 0; n < 4; ++n) {
            const int col = n0 + wc * 64 + n * 16 + lr;
            float v = acc[m][n][j];
            float gl = 0.5f * v * (1.f + erff(v * 0.70710678118654752f));  // exact gelu
            h[(size_t)grow * DFF_DIM + col] = f2b(gl);
          }
        }
      }
    } else {
      float* out = (float*)outp;
      #pragma unroll
      for (int m = 0; m < 8; ++m) {
        #pragma unroll
        for (int j = 0; j < 4; ++j) {
          const int p = tbase + wr * 128 + m * 16 + lq * 4 + j;
          if (p >= tlim) continue;
          const int tok = ptok[p];
          if (tok < 0) continue;
          const float g = pgate[p];
          #pragma unroll
          for (int n = 0; n < 4; ++n) {
            const int col = n0 + wc * 64 + n * 16 + lr;
            atomicAdd(&out[(size_t)tok * D_DIM + col], g * acc[m][n][j]);
          }
        }
      }
    }
#undef STAGE_ALL
#undef READ_A
#undef READ_B
#undef MFMA_Q
  }
}

// ---------------- launch ----------------
extern "C" void kernel_launch(void* const* d_in, const int* in_sizes, int n_in,
                              void* d_out, int out_size, void* d_ws, size_t ws_size,
                              hipStream_t stream) {
  const float* x  = (const float*)d_in[0];
  const float* rw = (const float*)d_in[1];
  const float* w1 = (const float*)d_in[2];
  const float* w2 = (const float*)d_in[3];
  float* out = (float*)d_out;

  char* ws = (char*)d_ws;
  unsigned short* xb   = (unsigned short*)(ws);              // 16,777,216
  unsigned short* w1t  = (unsigned short*)(ws + 16777216);   // 33,554,432  [16384][1024]
  unsigned short* w2t  = (unsigned short*)(ws + 50331648);   // 33,554,432  [1024][16384]
  unsigned short* h    = (unsigned short*)(ws + 83886080);   // 71,303,168  [17408][2048]
  int*   ptok   = (int*)(ws + 155189248);
  float* pgate  = (float*)(ws + 155258880);
  int*   sel    = (int*)(ws + 155328512);
  float* selw   = (float*)(ws + 155394048);
  int*   counts = (int*)(ws + 155459584);   // [0..7] counts
  int*   cursor  = counts + 8;              // [8..15]
  int*   padoff  = counts + 16;             // [16..23]
  int*   nitems  = counts + 24;             // [24..25] item counts, [28..29] work counters
  int*   tiles_e = counts + 32;
  int*   tiles_b = tiles_e + MAX_TILES256;
  int*   tiles_l = tiles_b + MAX_TILES256;
  unsigned short* zrow = (unsigned short*)(tiles_l + MAX_TILES256);  // 1040 zeros
  const size_t WS_NEED = 155459584 + 4096;
  if (ws_size < WS_NEED) return;

  hipFuncSetAttribute((const void*)gemm2p_kernel<0>,
                      hipFuncAttributeMaxDynamicSharedMemorySize, 131072);
  hipFuncSetAttribute((const void*)gemm2p_kernel<1>,
                      hipFuncAttributeMaxDynamicSharedMemorySize, 131072);

  hipMemsetAsync(out, 0, (size_t)T_TOK * D_DIM * sizeof(float), stream);
  hipMemsetAsync(counts, 0, 32 * sizeof(int), stream);  // counts/cursor/padoff/nitems+wcnt

  tcvt_kernel<<<dim3(16384 / 32, 1024 / 32), dim3(32, 8), 0, stream>>>(w1, w1t, 1024, 16384);
  tcvt_kernel<<<dim3(1024 / 32, 16384 / 32), dim3(32, 8), 0, stream>>>(w2, w2t, 16384, 1024);
  router_kernel<<<T_TOK / 4, 256, 0, stream>>>(x, rw, sel, selw, xb);
  count_kernel<<<2 * T_TOK / 256, 256, 0, stream>>>(sel, counts);
  plan_kernel<<<1, 256, 0, stream>>>(counts, tiles_e, tiles_b, tiles_l, padoff, cursor,
                                     nitems, ptok, pgate, zrow);
  scatter_kernel<<<T_TOK / 256, 256, 0, stream>>>(sel, selw, padoff, cursor, ptok, pgate);
  gemm2p_kernel<0><<<256, 512, 131072, stream>>>(
      xb, w1t, ptok, pgate, tiles_e, tiles_b, tiles_l, zrow, nitems, (void*)h);
  gemm2p_kernel<1><<<256, 512, 131072, stream>>>(
      h, w2t, ptok, pgate, tiles_e, tiles_b, tiles_l, zrow, nitems, (void*)out);
}

// Round 9
// 423.129 us; speedup vs baseline: 1.7910x; 1.7910x over previous
//
#include <hip/hip_runtime.h>
#include <hip/hip_bf16.h>

// Problem constants (B=4, S=2048, D=1024, E=8, K=2, DFF=2048)
#define T_TOK 8192
#define D_DIM 1024
#define E_NUM 8
#define TOPK 2
#define DFF_DIM 2048
#define BM 128
#define BK 64
#define MAX_TILES 136                 // sum_e ceil(count_e/128) <= 16384/128 + 8
#define MAX_PAIRS_PAD (MAX_TILES*BM)  // 17408

typedef __attribute__((ext_vector_type(8))) short short8_t;
typedef __attribute__((ext_vector_type(4))) float f32x4;

__device__ __forceinline__ unsigned short f2b(float f) {
  union { float f; unsigned u; } v; v.f = f;
  unsigned u = v.u;
  return (unsigned short)((u + 0x7fffu + ((u >> 16) & 1u)) >> 16);
}

__device__ __forceinline__ void gload_lds16(const void* g, void* l) {
  __builtin_amdgcn_global_load_lds(
      (const __attribute__((address_space(1))) unsigned int*)g,
      (__attribute__((address_space(3))) unsigned int*)l, 16, 0, 0);
}

// src[R][C] fp32 -> dst[C][R] bf16 (tiled transpose, coalesced both sides)
__global__ void tcvt_kernel(const float* __restrict__ src, unsigned short* __restrict__ dst,
                            int R, int C) {
  __shared__ float tile[32][33];
  int c0 = blockIdx.x * 32, r0 = blockIdx.y * 32;
  int tx = threadIdx.x, ty = threadIdx.y;  // 32x8
  #pragma unroll
  for (int i = 0; i < 32; i += 8)
    tile[ty + i][tx] = src[(size_t)(r0 + ty + i) * C + c0 + tx];
  __syncthreads();
  #pragma unroll
  for (int i = 0; i < 32; i += 8)
    dst[(size_t)(c0 + ty + i) * R + r0 + tx] = f2b(tile[tx][ty + i]);
}

// ---------------- router: logits, top-2, renorm; fused x->bf16; no hot atomics
__global__ void router_kernel(const float* __restrict__ x, const float* __restrict__ rw,
                              int* __restrict__ sel, float* __restrict__ selw,
                              unsigned short* __restrict__ xb) {
  int tok = (blockIdx.x * blockDim.x + threadIdx.x) >> 6;  // one wave per token
  int lane = threadIdx.x & 63;
  if (tok >= T_TOK) return;
  const float4* xr = (const float4*)(x + (size_t)tok * D_DIM);
  ushort4* xbr = (ushort4*)(xb + (size_t)tok * D_DIM);
  float acc[E_NUM];
  #pragma unroll
  for (int e = 0; e < E_NUM; ++e) acc[e] = 0.f;
  #pragma unroll
  for (int it = 0; it < 4; ++it) {
    int i = it * 64 + lane;      // float4 index, 0..255
    float4 v = xr[i];
    ushort4 o;
    o.x = f2b(v.x); o.y = f2b(v.y); o.z = f2b(v.z); o.w = f2b(v.w);
    xbr[i] = o;                  // fused bf16 conversion of x
    const float* w = rw + (size_t)i * 4 * E_NUM;
    #pragma unroll
    for (int e = 0; e < E_NUM; ++e) acc[e] += v.x * w[e];
    #pragma unroll
    for (int e = 0; e < E_NUM; ++e) acc[e] += v.y * w[E_NUM + e];
    #pragma unroll
    for (int e = 0; e < E_NUM; ++e) acc[e] += v.z * w[2 * E_NUM + e];
    #pragma unroll
    for (int e = 0; e < E_NUM; ++e) acc[e] += v.w * w[3 * E_NUM + e];
  }
  #pragma unroll
  for (int e = 0; e < E_NUM; ++e) {
    float v = acc[e];
    #pragma unroll
    for (int off = 32; off > 0; off >>= 1) v += __shfl_xor(v, off, 64);
    acc[e] = v;
  }
  if (lane == 0) {
    float mx = acc[0];
    #pragma unroll
    for (int e = 1; e < E_NUM; ++e) mx = fmaxf(mx, acc[e]);
    float p[E_NUM];
    #pragma unroll
    for (int e = 0; e < E_NUM; ++e) p[e] = __expf(acc[e] - mx);
    int i0 = 0;
    #pragma unroll
    for (int e = 1; e < E_NUM; ++e) if (p[e] > p[i0]) i0 = e;
    int i1 = (i0 == 0) ? 1 : 0;
    #pragma unroll
    for (int e = 0; e < E_NUM; ++e) if (e != i0 && p[e] > p[i1]) i1 = e;
    float w0 = p[i0], w1 = p[i1];
    float inv = 1.f / (w0 + w1);   // softmax denominator cancels in renorm
    sel[tok * 2] = i0; selw[tok * 2] = w0 * inv;
    sel[tok * 2 + 1] = i1; selw[tok * 2 + 1] = w1 * inv;
  }
}

// ---------------- counts: LDS-aggregated histogram ----------------
__global__ void count_kernel(const int* __restrict__ sel, int* __restrict__ counts) {
  __shared__ int lc[E_NUM];
  if (threadIdx.x < E_NUM) lc[threadIdx.x] = 0;
  __syncthreads();
  int t = blockIdx.x * blockDim.x + threadIdx.x;
  if (t < 2 * T_TOK) atomicAdd(&lc[sel[t]], 1);
  __syncthreads();
  if (threadIdx.x < E_NUM) atomicAdd(&counts[threadIdx.x], lc[threadIdx.x]);
}

// ---------------- plan: padded offsets + tile table + inits ----------------
__global__ void plan_kernel(const int* __restrict__ counts, int* __restrict__ tiles_e,
                            int* __restrict__ tiles_b, int* __restrict__ pad_off,
                            int* __restrict__ cursor, int* __restrict__ ptok,
                            float* __restrict__ pgate, unsigned short* __restrict__ zpad) {
  if (threadIdx.x == 0) {
    int b = 0, t = 0;
    for (int e = 0; e < E_NUM; ++e) {
      pad_off[e] = b;
      int nt = (counts[e] + BM - 1) >> 7;
      for (int i = 0; i < nt; ++i) { tiles_e[t] = e; tiles_b[t] = b + i * BM; ++t; }
      b += nt * BM;
    }
    for (; t < MAX_TILES; ++t) { tiles_e[t] = -1; tiles_b[t] = 0; }
  }
  for (int i = threadIdx.x; i < MAX_PAIRS_PAD; i += blockDim.x) { ptok[i] = -1; pgate[i] = 0.f; }
  for (int i = threadIdx.x; i < 64; i += blockDim.x) zpad[i] = 0;
  if (threadIdx.x < E_NUM) cursor[threadIdx.x] = 0;
}

// ---------------- scatter: block-level range reservation ----------------
__global__ void scatter_kernel(const int* __restrict__ sel, const float* __restrict__ selw,
                               const int* __restrict__ pad_off, int* __restrict__ cursor,
                               int* __restrict__ ptok, float* __restrict__ pgate) {
  __shared__ int lc[E_NUM];
  __shared__ int lbase[E_NUM];
  if (threadIdx.x < E_NUM) lc[threadIdx.x] = 0;
  __syncthreads();
  int t = blockIdx.x * blockDim.x + threadIdx.x;  // one thread per token
  int e0 = sel[t * 2], e1 = sel[t * 2 + 1];
  int o0 = atomicAdd(&lc[e0], 1);
  int o1 = atomicAdd(&lc[e1], 1);
  __syncthreads();
  if (threadIdx.x < E_NUM) lbase[threadIdx.x] = atomicAdd(&cursor[threadIdx.x], lc[threadIdx.x]);
  __syncthreads();
  int s0 = pad_off[e0] + lbase[e0] + o0;
  ptok[s0] = t; pgate[s0] = selw[t * 2];
  int s1 = pad_off[e1] + lbase[e1] + o1;
  ptok[s1] = t; pgate[s1] = selw[t * 2 + 1];
}

// ======== GEMM1: r3 structure + proven both-sides XOR swizzle ========
// h = gelu(X_gathered @ W1_e). LDS dest linear (gload_lds requirement);
// global source column chunk pre-permuted col8^(row&7); ds_read applies the
// same XOR: chunk = (ks*4+lq) ^ (lr&7)  [row&7 == lr&7 for all frag rows].
__global__ __launch_bounds__(256, 4) void gemm1_kernel(
    const unsigned short* __restrict__ xb, const unsigned short* __restrict__ w1t,
    const int* __restrict__ ptok, const int* __restrict__ tiles_e,
    const int* __restrict__ tiles_b, const unsigned short* __restrict__ zpad,
    unsigned short* __restrict__ h) {
  const int e = tiles_e[blockIdx.y];
  if (e < 0) return;
  const int base = tiles_b[blockIdx.y];
  const int n0 = blockIdx.x * 128;

  __shared__ unsigned short As[BM * BK];
  __shared__ unsigned short Bs[BM * BK];

  const int tid = threadIdx.x;
  const int lane = tid & 63;
  const int wv = tid >> 6;
  const int wr = wv >> 1, wc = wv & 1;
  const int lr = lane & 15;
  const int lq = lane >> 4;
  const int lsw = lr & 7;                     // read-side swizzle key

  int atok[4], aoff[4];
  const unsigned short* bptr[4];
  #pragma unroll
  for (int i = 0; i < 4; ++i) {
    int c = i * 256 + tid;
    int row = c >> 3, kc = c & 7;
    int kcs = kc ^ (row & 7);                 // inverse-swizzled source chunk
    atok[i] = ptok[base + row];
    aoff[i] = kcs * 8;
    bptr[i] = w1t + (size_t)(e * DFF_DIM + n0 + row) * D_DIM + kcs * 8;
  }

  f32x4 acc[4][4];
  #pragma unroll
  for (int m = 0; m < 4; ++m)
    #pragma unroll
    for (int n = 0; n < 4; ++n) acc[m][n] = (f32x4){0.f, 0.f, 0.f, 0.f};

  for (int k0 = 0; k0 < D_DIM; k0 += BK) {
    #pragma unroll
    for (int i = 0; i < 4; ++i) {
      const unsigned short* ga =
          (atok[i] >= 0) ? (xb + (size_t)atok[i] * D_DIM + k0 + aoff[i]) : zpad;
      gload_lds16(ga, &As[(i * 256 + tid) * 8]);          // LDS dest linear
      gload_lds16(bptr[i] + k0, &Bs[(i * 256 + tid) * 8]);
    }
    __syncthreads();
    #pragma unroll
    for (int kk = 0; kk < BK; kk += 32) {
      const int ch = (((kk >> 5) * 4 + lq) ^ lsw) * 8;    // swizzled read chunk
      short8_t aF[4], bF[4];
      #pragma unroll
      for (int m = 0; m < 4; ++m)
        aF[m] = *(const short8_t*)&As[(wr * 64 + m * 16 + lr) * BK + ch];
      #pragma unroll
      for (int n = 0; n < 4; ++n)
        bF[n] = *(const short8_t*)&Bs[(wc * 64 + n * 16 + lr) * BK + ch];
      #pragma unroll
      for (int m = 0; m < 4; ++m)
        #pragma unroll
        for (int n = 0; n < 4; ++n)
          acc[m][n] = __builtin_amdgcn_mfma_f32_16x16x32_bf16(aF[m], bF[n], acc[m][n], 0, 0, 0);
    }
    __syncthreads();
  }

  #pragma unroll
  for (int m = 0; m < 4; ++m) {
    #pragma unroll
    for (int n = 0; n < 4; ++n) {
      const int col = n0 + wc * 64 + n * 16 + lr;
      #pragma unroll
      for (int j = 0; j < 4; ++j) {
        const int row = base + wr * 64 + m * 16 + lq * 4 + j;
        float v = acc[m][n][j];
        float gl = 0.5f * v * (1.f + erff(v * 0.70710678118654752f));  // exact gelu
        h[(size_t)row * DFF_DIM + col] = f2b(gl);
      }
    }
  }
}

// ======== GEMM2: r3 structure + proven both-sides XOR swizzle ========
// out[tok] += gate * (h @ W2_e)
__global__ __launch_bounds__(256, 4) void gemm2_kernel(
    const unsigned short* __restrict__ h, const unsigned short* __restrict__ w2t,
    const int* __restrict__ ptok, const float* __restrict__ pgate,
    const int* __restrict__ tiles_e, const int* __restrict__ tiles_b,
    float* __restrict__ out) {
  const int e = tiles_e[blockIdx.y];
  if (e < 0) return;
  const int base = tiles_b[blockIdx.y];
  const int n0 = blockIdx.x * 128;

  __shared__ unsigned short As[BM * BK];
  __shared__ unsigned short Bs[BM * BK];

  const int tid = threadIdx.x;
  const int lane = tid & 63;
  const int wv = tid >> 6;
  const int wr = wv >> 1, wc = wv & 1;
  const int lr = lane & 15;
  const int lq = lane >> 4;
  const int lsw = lr & 7;

  const unsigned short* aptr[4];
  const unsigned short* bptr[4];
  #pragma unroll
  for (int i = 0; i < 4; ++i) {
    int c = i * 256 + tid;
    int row = c >> 3, kc = c & 7;
    int kcs = kc ^ (row & 7);                 // inverse-swizzled source chunk
    aptr[i] = h + (size_t)(base + row) * DFF_DIM + kcs * 8;
    bptr[i] = w2t + (size_t)(n0 + row) * (E_NUM * DFF_DIM) + e * DFF_DIM + kcs * 8;
  }

  f32x4 acc[4][4];
  #pragma unroll
  for (int m = 0; m < 4; ++m)
    #pragma unroll
    for (int n = 0; n < 4; ++n) acc[m][n] = (f32x4){0.f, 0.f, 0.f, 0.f};

  for (int k0 = 0; k0 < DFF_DIM; k0 += BK) {
    #pragma unroll
    for (int i = 0; i < 4; ++i) {
      gload_lds16(aptr[i] + k0, &As[(i * 256 + tid) * 8]);
      gload_lds16(bptr[i] + k0, &Bs[(i * 256 + tid) * 8]);
    }
    __syncthreads();
    #pragma unroll
    for (int kk = 0; kk < BK; kk += 32) {
      const int ch = (((kk >> 5) * 4 + lq) ^ lsw) * 8;
      short8_t aF[4], bF[4];
      #pragma unroll
      for (int m = 0; m < 4; ++m)
        aF[m] = *(const short8_t*)&As[(wr * 64 + m * 16 + lr) * BK + ch];
      #pragma unroll
      for (int n = 0; n < 4; ++n)
        bF[n] = *(const short8_t*)&Bs[(wc * 64 + n * 16 + lr) * BK + ch];
      #pragma unroll
      for (int m = 0; m < 4; ++m)
        #pragma unroll
        for (int n = 0; n < 4; ++n)
          acc[m][n] = __builtin_amdgcn_mfma_f32_16x16x32_bf16(aF[m], bF[n], acc[m][n], 0, 0, 0);
    }
    __syncthreads();
  }

  #pragma unroll
  for (int m = 0; m < 4; ++m) {
    #pragma unroll
    for (int j = 0; j < 4; ++j) {
      const int p = base + wr * 64 + m * 16 + lq * 4 + j;
      const int tok = ptok[p];
      if (tok < 0) continue;
      const float g = pgate[p];
      #pragma unroll
      for (int n = 0; n < 4; ++n) {
        const int col = n0 + wc * 64 + n * 16 + lr;
        atomicAdd(&out[(size_t)tok * D_DIM + col], g * acc[m][n][j]);
      }
    }
  }
}

// ---------------- launch ----------------
extern "C" void kernel_launch(void* const* d_in, const int* in_sizes, int n_in,
                              void* d_out, int out_size, void* d_ws, size_t ws_size,
                              hipStream_t stream) {
  const float* x  = (const float*)d_in[0];
  const float* rw = (const float*)d_in[1];
  const float* w1 = (const float*)d_in[2];
  const float* w2 = (const float*)d_in[3];
  float* out = (float*)d_out;

  char* ws = (char*)d_ws;
  unsigned short* xb   = (unsigned short*)(ws);              // 16,777,216
  unsigned short* w1t  = (unsigned short*)(ws + 16777216);   // 33,554,432  [16384][1024]
  unsigned short* w2t  = (unsigned short*)(ws + 50331648);   // 33,554,432  [1024][16384]
  unsigned short* h    = (unsigned short*)(ws + 83886080);   // 71,303,168  [17408][2048]
  int*   ptok   = (int*)(ws + 155189248);
  float* pgate  = (float*)(ws + 155258880);
  int*   sel    = (int*)(ws + 155328512);
  float* selw   = (float*)(ws + 155394048);
  int*   counts = (int*)(ws + 155459584);
  int*   cursor = counts + 8;
  int*   padoff = counts + 16;
  int*   tiles_e = counts + 24;
  int*   tiles_b = tiles_e + MAX_TILES;
  unsigned short* zpad = (unsigned short*)(tiles_b + MAX_TILES);
  const size_t WS_NEED = 155459584 + 4096;
  if (ws_size < WS_NEED) return;

  hipMemsetAsync(out, 0, (size_t)T_TOK * D_DIM * sizeof(float), stream);
  hipMemsetAsync(counts, 0, E_NUM * sizeof(int), stream);

  tcvt_kernel<<<dim3(16384 / 32, 1024 / 32), dim3(32, 8), 0, stream>>>(w1, w1t, 1024, 16384);
  tcvt_kernel<<<dim3(1024 / 32, 16384 / 32), dim3(32, 8), 0, stream>>>(w2, w2t, 16384, 1024);
  router_kernel<<<T_TOK / 4, 256, 0, stream>>>(x, rw, sel, selw, xb);
  count_kernel<<<2 * T_TOK / 256, 256, 0, stream>>>(sel, counts);
  plan_kernel<<<1, 256, 0, stream>>>(counts, tiles_e, tiles_b, padoff, cursor, ptok, pgate, zpad);
  scatter_kernel<<<T_TOK / 256, 256, 0, stream>>>(sel, selw, padoff, cursor, ptok, pgate);
  gemm1_kernel<<<dim3(DFF_DIM / 128, MAX_TILES), 256, 0, stream>>>(xb, w1t, ptok, tiles_e,
                                                                   tiles_b, zpad, h);
  gemm2_kernel<<<dim3(D_DIM / 128, MAX_TILES), 256, 0, stream>>>(h, w2t, ptok, pgate, tiles_e,
                                                                 tiles_b, out);
}

// Round 10
// 341.194 us; speedup vs baseline: 2.2211x; 1.2401x over previous
//
#include <hip/hip_runtime.h>
#include <hip/hip_bf16.h>

// Problem constants (B=4, S=2048, D=1024, E=8, K=2, DFF=2048)
#define T_TOK 8192
#define D_DIM 1024
#define E_NUM 8
#define TOPK 2
#define DFF_DIM 2048
#define BM 128
#define BK 64
#define MAX_TILES 136                 // sum_e ceil(count_e/128) <= 16384/128 + 8
#define MAX_PAIRS_PAD (MAX_TILES*BM)  // 17408

typedef __attribute__((ext_vector_type(8))) short short8_t;
typedef __attribute__((ext_vector_type(4))) float f32x4;

__device__ __forceinline__ unsigned short f2b(float f) {
  union { float f; unsigned u; } v; v.f = f;
  unsigned u = v.u;
  return (unsigned short)((u + 0x7fffu + ((u >> 16) & 1u)) >> 16);
}

__device__ __forceinline__ void gload_lds16(const void* g, void* l) {
  __builtin_amdgcn_global_load_lds(
      (const __attribute__((address_space(1))) unsigned int*)g,
      (__attribute__((address_space(3))) unsigned int*)l, 16, 0, 0);
}

// src[R][C] fp32 -> dst[C][R] bf16 (tiled transpose, coalesced both sides)
__global__ void tcvt_kernel(const float* __restrict__ src, unsigned short* __restrict__ dst,
                            int R, int C) {
  __shared__ float tile[32][33];
  int c0 = blockIdx.x * 32, r0 = blockIdx.y * 32;
  int tx = threadIdx.x, ty = threadIdx.y;  // 32x8
  #pragma unroll
  for (int i = 0; i < 32; i += 8)
    tile[ty + i][tx] = src[(size_t)(r0 + ty + i) * C + c0 + tx];
  __syncthreads();
  #pragma unroll
  for (int i = 0; i < 32; i += 8)
    dst[(size_t)(c0 + ty + i) * R + r0 + tx] = f2b(tile[tx][ty + i]);
}

// ---------------- router: logits, top-2, renorm; fused x->bf16; no hot atomics
__global__ void router_kernel(const float* __restrict__ x, const float* __restrict__ rw,
                              int* __restrict__ sel, float* __restrict__ selw,
                              unsigned short* __restrict__ xb) {
  int tok = (blockIdx.x * blockDim.x + threadIdx.x) >> 6;  // one wave per token
  int lane = threadIdx.x & 63;
  if (tok >= T_TOK) return;
  const float4* xr = (const float4*)(x + (size_t)tok * D_DIM);
  ushort4* xbr = (ushort4*)(xb + (size_t)tok * D_DIM);
  float acc[E_NUM];
  #pragma unroll
  for (int e = 0; e < E_NUM; ++e) acc[e] = 0.f;
  #pragma unroll
  for (int it = 0; it < 4; ++it) {
    int i = it * 64 + lane;      // float4 index, 0..255
    float4 v = xr[i];
    ushort4 o;
    o.x = f2b(v.x); o.y = f2b(v.y); o.z = f2b(v.z); o.w = f2b(v.w);
    xbr[i] = o;                  // fused bf16 conversion of x
    const float* w = rw + (size_t)i * 4 * E_NUM;
    #pragma unroll
    for (int e = 0; e < E_NUM; ++e) acc[e] += v.x * w[e];
    #pragma unroll
    for (int e = 0; e < E_NUM; ++e) acc[e] += v.y * w[E_NUM + e];
    #pragma unroll
    for (int e = 0; e < E_NUM; ++e) acc[e] += v.z * w[2 * E_NUM + e];
    #pragma unroll
    for (int e = 0; e < E_NUM; ++e) acc[e] += v.w * w[3 * E_NUM + e];
  }
  #pragma unroll
  for (int e = 0; e < E_NUM; ++e) {
    float v = acc[e];
    #pragma unroll
    for (int off = 32; off > 0; off >>= 1) v += __shfl_xor(v, off, 64);
    acc[e] = v;
  }
  if (lane == 0) {
    float mx = acc[0];
    #pragma unroll
    for (int e = 1; e < E_NUM; ++e) mx = fmaxf(mx, acc[e]);
    float p[E_NUM];
    #pragma unroll
    for (int e = 0; e < E_NUM; ++e) p[e] = __expf(acc[e] - mx);
    int i0 = 0;
    #pragma unroll
    for (int e = 1; e < E_NUM; ++e) if (p[e] > p[i0]) i0 = e;
    int i1 = (i0 == 0) ? 1 : 0;
    #pragma unroll
    for (int e = 0; e < E_NUM; ++e) if (e != i0 && p[e] > p[i1]) i1 = e;
    float w0 = p[i0], w1 = p[i1];
    float inv = 1.f / (w0 + w1);   // softmax denominator cancels in renorm
    sel[tok * 2] = i0; selw[tok * 2] = w0 * inv;
    sel[tok * 2 + 1] = i1; selw[tok * 2 + 1] = w1 * inv;
  }
}

// ---------------- counts: LDS-aggregated histogram ----------------
__global__ void count_kernel(const int* __restrict__ sel, int* __restrict__ counts) {
  __shared__ int lc[E_NUM];
  if (threadIdx.x < E_NUM) lc[threadIdx.x] = 0;
  __syncthreads();
  int t = blockIdx.x * blockDim.x + threadIdx.x;
  if (t < 2 * T_TOK) atomicAdd(&lc[sel[t]], 1);
  __syncthreads();
  if (threadIdx.x < E_NUM) atomicAdd(&counts[threadIdx.x], lc[threadIdx.x]);
}

// ---------------- plan: padded offsets + tile table + inits ----------------
__global__ void plan_kernel(const int* __restrict__ counts, int* __restrict__ tiles_e,
                            int* __restrict__ tiles_b, int* __restrict__ pad_off,
                            int* __restrict__ cursor, int* __restrict__ ptok,
                            float* __restrict__ pgate, unsigned short* __restrict__ zpad) {
  if (threadIdx.x == 0) {
    int b = 0, t = 0;
    for (int e = 0; e < E_NUM; ++e) {
      pad_off[e] = b;
      int nt = (counts[e] + BM - 1) >> 7;
      for (int i = 0; i < nt; ++i) { tiles_e[t] = e; tiles_b[t] = b + i * BM; ++t; }
      b += nt * BM;
    }
    for (; t < MAX_TILES; ++t) { tiles_e[t] = -1; tiles_b[t] = 0; }
  }
  for (int i = threadIdx.x; i < MAX_PAIRS_PAD; i += blockDim.x) { ptok[i] = -1; pgate[i] = 0.f; }
  for (int i = threadIdx.x; i < 64; i += blockDim.x) zpad[i] = 0;
  if (threadIdx.x < E_NUM) cursor[threadIdx.x] = 0;
}

// ---------------- scatter: block-level range reservation ----------------
__global__ void scatter_kernel(const int* __restrict__ sel, const float* __restrict__ selw,
                               const int* __restrict__ pad_off, int* __restrict__ cursor,
                               int* __restrict__ ptok, float* __restrict__ pgate) {
  __shared__ int lc[E_NUM];
  __shared__ int lbase[E_NUM];
  if (threadIdx.x < E_NUM) lc[threadIdx.x] = 0;
  __syncthreads();
  int t = blockIdx.x * blockDim.x + threadIdx.x;  // one thread per token
  int e0 = sel[t * 2], e1 = sel[t * 2 + 1];
  int o0 = atomicAdd(&lc[e0], 1);
  int o1 = atomicAdd(&lc[e1], 1);
  __syncthreads();
  if (threadIdx.x < E_NUM) lbase[threadIdx.x] = atomicAdd(&cursor[threadIdx.x], lc[threadIdx.x]);
  __syncthreads();
  int s0 = pad_off[e0] + lbase[e0] + o0;
  ptok[s0] = t; pgate[s0] = selw[t * 2];
  int s1 = pad_off[e1] + lbase[e1] + o1;
  ptok[s1] = t; pgate[s1] = selw[t * 2 + 1];
}

// ======== GEMM1: r3 structure + 0-conflict swizzle; launch_bounds (256,2) ====
// h = gelu(X_gathered @ W1_e). LDS dest linear (gload_lds requirement);
// global source column chunk pre-permuted col8^(row&7); ds_read applies the
// same XOR: chunk = (ks*4+lq) ^ (lr&7)  [row&7 == lr&7 for all frag rows].
__global__ __launch_bounds__(256, 2) void gemm1_kernel(
    const unsigned short* __restrict__ xb, const unsigned short* __restrict__ w1t,
    const int* __restrict__ ptok, const int* __restrict__ tiles_e,
    const int* __restrict__ tiles_b, const unsigned short* __restrict__ zpad,
    unsigned short* __restrict__ h) {
  const int e = tiles_e[blockIdx.y];
  if (e < 0) return;
  const int base = tiles_b[blockIdx.y];
  const int n0 = blockIdx.x * 128;

  __shared__ unsigned short As[BM * BK];
  __shared__ unsigned short Bs[BM * BK];

  const int tid = threadIdx.x;
  const int lane = tid & 63;
  const int wv = tid >> 6;
  const int wr = wv >> 1, wc = wv & 1;
  const int lr = lane & 15;
  const int lq = lane >> 4;
  const int lsw = lr & 7;                     // read-side swizzle key

  int atok[4], aoff[4];
  const unsigned short* bptr[4];
  #pragma unroll
  for (int i = 0; i < 4; ++i) {
    int c = i * 256 + tid;
    int row = c >> 3, kc = c & 7;
    int kcs = kc ^ (row & 7);                 // inverse-swizzled source chunk
    atok[i] = ptok[base + row];
    aoff[i] = kcs * 8;
    bptr[i] = w1t + (size_t)(e * DFF_DIM + n0 + row) * D_DIM + kcs * 8;
  }

  f32x4 acc[4][4];
  #pragma unroll
  for (int m = 0; m < 4; ++m)
    #pragma unroll
    for (int n = 0; n < 4; ++n) acc[m][n] = (f32x4){0.f, 0.f, 0.f, 0.f};

  for (int k0 = 0; k0 < D_DIM; k0 += BK) {
    #pragma unroll
    for (int i = 0; i < 4; ++i) {
      const unsigned short* ga =
          (atok[i] >= 0) ? (xb + (size_t)atok[i] * D_DIM + k0 + aoff[i]) : zpad;
      gload_lds16(ga, &As[(i * 256 + tid) * 8]);          // LDS dest linear
      gload_lds16(bptr[i] + k0, &Bs[(i * 256 + tid) * 8]);
    }
    __syncthreads();
    #pragma unroll
    for (int kk = 0; kk < BK; kk += 32) {
      const int ch = (((kk >> 5) * 4 + lq) ^ lsw) * 8;    // swizzled read chunk
      short8_t aF[4], bF[4];
      #pragma unroll
      for (int m = 0; m < 4; ++m)
        aF[m] = *(const short8_t*)&As[(wr * 64 + m * 16 + lr) * BK + ch];
      #pragma unroll
      for (int n = 0; n < 4; ++n)
        bF[n] = *(const short8_t*)&Bs[(wc * 64 + n * 16 + lr) * BK + ch];
      #pragma unroll
      for (int m = 0; m < 4; ++m)
        #pragma unroll
        for (int n = 0; n < 4; ++n)
          acc[m][n] = __builtin_amdgcn_mfma_f32_16x16x32_bf16(aF[m], bF[n], acc[m][n], 0, 0, 0);
    }
    __syncthreads();
  }

  #pragma unroll
  for (int m = 0; m < 4; ++m) {
    #pragma unroll
    for (int n = 0; n < 4; ++n) {
      const int col = n0 + wc * 64 + n * 16 + lr;
      #pragma unroll
      for (int j = 0; j < 4; ++j) {
        const int row = base + wr * 64 + m * 16 + lq * 4 + j;
        float v = acc[m][n][j];
        float gl = 0.5f * v * (1.f + erff(v * 0.70710678118654752f));  // exact gelu
        h[(size_t)row * DFF_DIM + col] = f2b(gl);
      }
    }
  }
}

// ======== GEMM2: r3 structure + 0-conflict swizzle; launch_bounds (256,2) ====
// out[tok] += gate * (h @ W2_e)
__global__ __launch_bounds__(256, 2) void gemm2_kernel(
    const unsigned short* __restrict__ h, const unsigned short* __restrict__ w2t,
    const int* __restrict__ ptok, const float* __restrict__ pgate,
    const int* __restrict__ tiles_e, const int* __restrict__ tiles_b,
    float* __restrict__ out) {
  const int e = tiles_e[blockIdx.y];
  if (e < 0) return;
  const int base = tiles_b[blockIdx.y];
  const int n0 = blockIdx.x * 128;

  __shared__ unsigned short As[BM * BK];
  __shared__ unsigned short Bs[BM * BK];

  const int tid = threadIdx.x;
  const int lane = tid & 63;
  const int wv = tid >> 6;
  const int wr = wv >> 1, wc = wv & 1;
  const int lr = lane & 15;
  const int lq = lane >> 4;
  const int lsw = lr & 7;

  const unsigned short* aptr[4];
  const unsigned short* bptr[4];
  #pragma unroll
  for (int i = 0; i < 4; ++i) {
    int c = i * 256 + tid;
    int row = c >> 3, kc = c & 7;
    int kcs = kc ^ (row & 7);                 // inverse-swizzled source chunk
    aptr[i] = h + (size_t)(base + row) * DFF_DIM + kcs * 8;
    bptr[i] = w2t + (size_t)(n0 + row) * (E_NUM * DFF_DIM) + e * DFF_DIM + kcs * 8;
  }

  f32x4 acc[4][4];
  #pragma unroll
  for (int m = 0; m < 4; ++m)
    #pragma unroll
    for (int n = 0; n < 4; ++n) acc[m][n] = (f32x4){0.f, 0.f, 0.f, 0.f};

  for (int k0 = 0; k0 < DFF_DIM; k0 += BK) {
    #pragma unroll
    for (int i = 0; i < 4; ++i) {
      gload_lds16(aptr[i] + k0, &As[(i * 256 + tid) * 8]);
      gload_lds16(bptr[i] + k0, &Bs[(i * 256 + tid) * 8]);
    }
    __syncthreads();
    #pragma unroll
    for (int kk = 0; kk < BK; kk += 32) {
      const int ch = (((kk >> 5) * 4 + lq) ^ lsw) * 8;
      short8_t aF[4], bF[4];
      #pragma unroll
      for (int m = 0; m < 4; ++m)
        aF[m] = *(const short8_t*)&As[(wr * 64 + m * 16 + lr) * BK + ch];
      #pragma unroll
      for (int n = 0; n < 4; ++n)
        bF[n] = *(const short8_t*)&Bs[(wc * 64 + n * 16 + lr) * BK + ch];
      #pragma unroll
      for (int m = 0; m < 4; ++m)
        #pragma unroll
        for (int n = 0; n < 4; ++n)
          acc[m][n] = __builtin_amdgcn_mfma_f32_16x16x32_bf16(aF[m], bF[n], acc[m][n], 0, 0, 0);
    }
    __syncthreads();
  }

  #pragma unroll
  for (int m = 0; m < 4; ++m) {
    #pragma unroll
    for (int j = 0; j < 4; ++j) {
      const int p = base + wr * 64 + m * 16 + lq * 4 + j;
      const int tok = ptok[p];
      if (tok < 0) continue;
      const float g = pgate[p];
      #pragma unroll
      for (int n = 0; n < 4; ++n) {
        const int col = n0 + wc * 64 + n * 16 + lr;
        atomicAdd(&out[(size_t)tok * D_DIM + col], g * acc[m][n][j]);
      }
    }
  }
}

// ---------------- launch ----------------
extern "C" void kernel_launch(void* const* d_in, const int* in_sizes, int n_in,
                              void* d_out, int out_size, void* d_ws, size_t ws_size,
                              hipStream_t stream) {
  const float* x  = (const float*)d_in[0];
  const float* rw = (const float*)d_in[1];
  const float* w1 = (const float*)d_in[2];
  const float* w2 = (const float*)d_in[3];
  float* out = (float*)d_out;

  char* ws = (char*)d_ws;
  unsigned short* xb   = (unsigned short*)(ws);              // 16,777,216
  unsigned short* w1t  = (unsigned short*)(ws + 16777216);   // 33,554,432  [16384][1024]
  unsigned short* w2t  = (unsigned short*)(ws + 50331648);   // 33,554,432  [1024][16384]
  unsigned short* h    = (unsigned short*)(ws + 83886080);   // 71,303,168  [17408][2048]
  int*   ptok   = (int*)(ws + 155189248);
  float* pgate  = (float*)(ws + 155258880);
  int*   sel    = (int*)(ws + 155328512);
  float* selw   = (float*)(ws + 155394048);
  int*   counts = (int*)(ws + 155459584);
  int*   cursor = counts + 8;
  int*   padoff = counts + 16;
  int*   tiles_e = counts + 24;
  int*   tiles_b = tiles_e + MAX_TILES;
  unsigned short* zpad = (unsigned short*)(tiles_b + MAX_TILES);
  const size_t WS_NEED = 155459584 + 4096;
  if (ws_size < WS_NEED) return;

  hipMemsetAsync(out, 0, (size_t)T_TOK * D_DIM * sizeof(float), stream);
  hipMemsetAsync(counts, 0, E_NUM * sizeof(int), stream);

  tcvt_kernel<<<dim3(16384 / 32, 1024 / 32), dim3(32, 8), 0, stream>>>(w1, w1t, 1024, 16384);
  tcvt_kernel<<<dim3(1024 / 32, 16384 / 32), dim3(32, 8), 0, stream>>>(w2, w2t, 16384, 1024);
  router_kernel<<<T_TOK / 4, 256, 0, stream>>>(x, rw, sel, selw, xb);
  count_kernel<<<2 * T_TOK / 256, 256, 0, stream>>>(sel, counts);
  plan_kernel<<<1, 256, 0, stream>>>(counts, tiles_e, tiles_b, padoff, cursor, ptok, pgate, zpad);
  scatter_kernel<<<T_TOK / 256, 256, 0, stream>>>(sel, selw, padoff, cursor, ptok, pgate);
  gemm1_kernel<<<dim3(DFF_DIM / 128, MAX_TILES), 256, 0, stream>>>(xb, w1t, ptok, tiles_e,
                                                                   tiles_b, zpad, h);
  gemm2_kernel<<<dim3(D_DIM / 128, MAX_TILES), 256, 0, stream>>>(h, w2t, ptok, pgate, tiles_e,
                                                                 tiles_b, out);
}

// Round 12
// 325.814 us; speedup vs baseline: 2.3260x; 1.0472x over previous
//
#include <hip/hip_runtime.h>
#include <hip/hip_bf16.h>

// Problem constants (B=4, S=2048, D=1024, E=8, K=2, DFF=2048)
#define T_TOK 8192
#define D_DIM 1024
#define E_NUM 8
#define TOPK 2
#define DFF_DIM 2048
#define BM 128
#define BK 64
#define MAX_TILES 136                 // 17 * 8: per-XCD chunking is exactly bijective
#define MAX_PAIRS_PAD (MAX_TILES*BM)  // 17408

typedef __attribute__((ext_vector_type(8))) short short8_t;
typedef __attribute__((ext_vector_type(4))) float f32x4;

__device__ __forceinline__ unsigned short f2b(float f) {
  union { float f; unsigned u; } v; v.f = f;
  unsigned u = v.u;
  return (unsigned short)((u + 0x7fffu + ((u >> 16) & 1u)) >> 16);
}

__device__ __forceinline__ void gload_lds16(const void* g, void* l) {
  __builtin_amdgcn_global_load_lds(
      (const __attribute__((address_space(1))) unsigned int*)g,
      (__attribute__((address_space(3))) unsigned int*)l, 16, 0, 0);
}

// src[R][C] fp32 -> dst[C][R] bf16 (tiled transpose, coalesced both sides)
__global__ void tcvt_kernel(const float* __restrict__ src, unsigned short* __restrict__ dst,
                            int R, int C) {
  __shared__ float tile[32][33];
  int c0 = blockIdx.x * 32, r0 = blockIdx.y * 32;
  int tx = threadIdx.x, ty = threadIdx.y;  // 32x8
  #pragma unroll
  for (int i = 0; i < 32; i += 8)
    tile[ty + i][tx] = src[(size_t)(r0 + ty + i) * C + c0 + tx];
  __syncthreads();
  #pragma unroll
  for (int i = 0; i < 32; i += 8)
    dst[(size_t)(c0 + ty + i) * R + r0 + tx] = f2b(tile[tx][ty + i]);
}

// ---------------- router: logits, top-2, renorm; fused x->bf16; no hot atomics
__global__ void router_kernel(const float* __restrict__ x, const float* __restrict__ rw,
                              int* __restrict__ sel, float* __restrict__ selw,
                              unsigned short* __restrict__ xb) {
  int tok = (blockIdx.x * blockDim.x + threadIdx.x) >> 6;  // one wave per token
  int lane = threadIdx.x & 63;
  if (tok >= T_TOK) return;
  const float4* xr = (const float4*)(x + (size_t)tok * D_DIM);
  ushort4* xbr = (ushort4*)(xb + (size_t)tok * D_DIM);
  float acc[E_NUM];
  #pragma unroll
  for (int e = 0; e < E_NUM; ++e) acc[e] = 0.f;
  #pragma unroll
  for (int it = 0; it < 4; ++it) {
    int i = it * 64 + lane;      // float4 index, 0..255
    float4 v = xr[i];
    ushort4 o;
    o.x = f2b(v.x); o.y = f2b(v.y); o.z = f2b(v.z); o.w = f2b(v.w);
    xbr[i] = o;                  // fused bf16 conversion of x
    const float* w = rw + (size_t)i * 4 * E_NUM;
    #pragma unroll
    for (int e = 0; e < E_NUM; ++e) acc[e] += v.x * w[e];
    #pragma unroll
    for (int e = 0; e < E_NUM; ++e) acc[e] += v.y * w[E_NUM + e];
    #pragma unroll
    for (int e = 0; e < E_NUM; ++e) acc[e] += v.z * w[2 * E_NUM + e];
    #pragma unroll
    for (int e = 0; e < E_NUM; ++e) acc[e] += v.w * w[3 * E_NUM + e];
  }
  #pragma unroll
  for (int e = 0; e < E_NUM; ++e) {
    float v = acc[e];
    #pragma unroll
    for (int off = 32; off > 0; off >>= 1) v += __shfl_xor(v, off, 64);
    acc[e] = v;
  }
  if (lane == 0) {
    float mx = acc[0];
    #pragma unroll
    for (int e = 1; e < E_NUM; ++e) mx = fmaxf(mx, acc[e]);
    float p[E_NUM];
    #pragma unroll
    for (int e = 0; e < E_NUM; ++e) p[e] = __expf(acc[e] - mx);
    int i0 = 0;
    #pragma unroll
    for (int e = 1; e < E_NUM; ++e) if (p[e] > p[i0]) i0 = e;
    int i1 = (i0 == 0) ? 1 : 0;
    #pragma unroll
    for (int e = 0; e < E_NUM; ++e) if (e != i0 && p[e] > p[i1]) i1 = e;
    float w0 = p[i0], w1 = p[i1];
    float inv = 1.f / (w0 + w1);   // softmax denominator cancels in renorm
    sel[tok * 2] = i0; selw[tok * 2] = w0 * inv;
    sel[tok * 2 + 1] = i1; selw[tok * 2 + 1] = w1 * inv;
  }
}

// ---------------- counts: LDS-aggregated histogram ----------------
__global__ void count_kernel(const int* __restrict__ sel, int* __restrict__ counts) {
  __shared__ int lc[E_NUM];
  if (threadIdx.x < E_NUM) lc[threadIdx.x] = 0;
  __syncthreads();
  int t = blockIdx.x * blockDim.x + threadIdx.x;
  if (t < 2 * T_TOK) atomicAdd(&lc[sel[t]], 1);
  __syncthreads();
  if (threadIdx.x < E_NUM) atomicAdd(&counts[threadIdx.x], lc[threadIdx.x]);
}

// ---------------- plan: padded offsets + tile table + inits ----------------
__global__ void plan_kernel(const int* __restrict__ counts, int* __restrict__ tiles_e,
                            int* __restrict__ tiles_b, int* __restrict__ pad_off,
                            int* __restrict__ cursor, int* __restrict__ ptok,
                            float* __restrict__ pgate, unsigned short* __restrict__ zpad) {
  if (threadIdx.x == 0) {
    int b = 0, t = 0;
    for (int e = 0; e < E_NUM; ++e) {
      pad_off[e] = b;
      int nt = (counts[e] + BM - 1) >> 7;
      for (int i = 0; i < nt; ++i) { tiles_e[t] = e; tiles_b[t] = b + i * BM; ++t; }
      b += nt * BM;
    }
    for (; t < MAX_TILES; ++t) { tiles_e[t] = -1; tiles_b[t] = 0; }
  }
  for (int i = threadIdx.x; i < MAX_PAIRS_PAD; i += blockDim.x) { ptok[i] = -1; pgate[i] = 0.f; }
  for (int i = threadIdx.x; i < 64; i += blockDim.x) zpad[i] = 0;
  if (threadIdx.x < E_NUM) cursor[threadIdx.x] = 0;
}

// ---------------- scatter: block-level range reservation ----------------
__global__ void scatter_kernel(const int* __restrict__ sel, const float* __restrict__ selw,
                               const int* __restrict__ pad_off, int* __restrict__ cursor,
                               int* __restrict__ ptok, float* __restrict__ pgate) {
  __shared__ int lc[E_NUM];
  __shared__ int lbase[E_NUM];
  if (threadIdx.x < E_NUM) lc[threadIdx.x] = 0;
  __syncthreads();
  int t = blockIdx.x * blockDim.x + threadIdx.x;  // one thread per token
  int e0 = sel[t * 2], e1 = sel[t * 2 + 1];
  int o0 = atomicAdd(&lc[e0], 1);
  int o1 = atomicAdd(&lc[e1], 1);
  __syncthreads();
  if (threadIdx.x < E_NUM) lbase[threadIdx.x] = atomicAdd(&cursor[threadIdx.x], lc[threadIdx.x]);
  __syncthreads();
  int s0 = pad_off[e0] + lbase[e0] + o0;
  ptok[s0] = t; pgate[s0] = selw[t * 2];
  int s1 = pad_off[e1] + lbase[e1] + o1;
  ptok[s1] = t; pgate[s1] = selw[t * 2 + 1];
}

// ======== GEMM1: r10 + T1 XCD-chunked block swizzle (NX=16) ========
// id = bx + 16*by; xcd = id&7 owns tiles [17*xcd, 17*xcd+17) and ALL their
// n-blocks -> shared A-tile and same-expert B panels stay in one XCD's L2.
__global__ __launch_bounds__(256, 2) void gemm1_kernel(
    const unsigned short* __restrict__ xb, const unsigned short* __restrict__ w1t,
    const int* __restrict__ ptok, const int* __restrict__ tiles_e,
    const int* __restrict__ tiles_b, const unsigned short* __restrict__ zpad,
    unsigned short* __restrict__ h) {
  const int id = blockIdx.x + 16 * blockIdx.y;
  const int xcd = id & 7;
  const int j = id >> 3;                     // 0..271 per XCD
  const int tileIdx = xcd * 17 + (j >> 4);   // 17 tiles per XCD
  const int n0 = (j & 15) * 128;
  const int e = tiles_e[tileIdx];
  if (e < 0) return;
  const int base = tiles_b[tileIdx];

  __shared__ unsigned short As[BM * BK];
  __shared__ unsigned short Bs[BM * BK];

  const int tid = threadIdx.x;
  const int lane = tid & 63;
  const int wv = tid >> 6;
  const int wr = wv >> 1, wc = wv & 1;
  const int lr = lane & 15;
  const int lq = lane >> 4;
  const int lsw = lr & 7;                     // read-side swizzle key

  int atok[4], aoff[4];
  const unsigned short* bptr[4];
  #pragma unroll
  for (int i = 0; i < 4; ++i) {
    int c = i * 256 + tid;
    int row = c >> 3, kc = c & 7;
    int kcs = kc ^ (row & 7);                 // inverse-swizzled source chunk
    atok[i] = ptok[base + row];
    aoff[i] = kcs * 8;
    bptr[i] = w1t + (size_t)(e * DFF_DIM + n0 + row) * D_DIM + kcs * 8;
  }

  f32x4 acc[4][4];
  #pragma unroll
  for (int m = 0; m < 4; ++m)
    #pragma unroll
    for (int n = 0; n < 4; ++n) acc[m][n] = (f32x4){0.f, 0.f, 0.f, 0.f};

  for (int k0 = 0; k0 < D_DIM; k0 += BK) {
    #pragma unroll
    for (int i = 0; i < 4; ++i) {
      const unsigned short* ga =
          (atok[i] >= 0) ? (xb + (size_t)atok[i] * D_DIM + k0 + aoff[i]) : zpad;
      gload_lds16(ga, &As[(i * 256 + tid) * 8]);          // LDS dest linear
      gload_lds16(bptr[i] + k0, &Bs[(i * 256 + tid) * 8]);
    }
    __syncthreads();
    #pragma unroll
    for (int kk = 0; kk < BK; kk += 32) {
      const int ch = (((kk >> 5) * 4 + lq) ^ lsw) * 8;    // swizzled read chunk
      short8_t aF[4], bF[4];
      #pragma unroll
      for (int m = 0; m < 4; ++m)
        aF[m] = *(const short8_t*)&As[(wr * 64 + m * 16 + lr) * BK + ch];
      #pragma unroll
      for (int n = 0; n < 4; ++n)
        bF[n] = *(const short8_t*)&Bs[(wc * 64 + n * 16 + lr) * BK + ch];
      #pragma unroll
      for (int m = 0; m < 4; ++m)
        #pragma unroll
        for (int n = 0; n < 4; ++n)
          acc[m][n] = __builtin_amdgcn_mfma_f32_16x16x32_bf16(aF[m], bF[n], acc[m][n], 0, 0, 0);
    }
    __syncthreads();
  }

  #pragma unroll
  for (int m = 0; m < 4; ++m) {
    #pragma unroll
    for (int n = 0; n < 4; ++n) {
      const int col = n0 + wc * 64 + n * 16 + lr;
      #pragma unroll
      for (int j4 = 0; j4 < 4; ++j4) {
        const int row = base + wr * 64 + m * 16 + lq * 4 + j4;
        float v = acc[m][n][j4];
        float gl = 0.5f * v * (1.f + erff(v * 0.70710678118654752f));  // exact gelu
        h[(size_t)row * DFF_DIM + col] = f2b(gl);
      }
    }
  }
}

// ======== GEMM2: r10 + T1 XCD-chunked block swizzle (NX=8) ========
// out[tok] += gate * (h @ W2_e)
__global__ __launch_bounds__(256, 2) void gemm2_kernel(
    const unsigned short* __restrict__ h, const unsigned short* __restrict__ w2t,
    const int* __restrict__ ptok, const float* __restrict__ pgate,
    const int* __restrict__ tiles_e, const int* __restrict__ tiles_b,
    float* __restrict__ out) {
  const int id = blockIdx.x + 8 * blockIdx.y;
  const int xcd = id & 7;
  const int j = id >> 3;                     // 0..135 per XCD
  const int tileIdx = xcd * 17 + (j >> 3);   // 17 tiles per XCD
  const int n0 = (j & 7) * 128;
  const int e = tiles_e[tileIdx];
  if (e < 0) return;
  const int base = tiles_b[tileIdx];

  __shared__ unsigned short As[BM * BK];
  __shared__ unsigned short Bs[BM * BK];

  const int tid = threadIdx.x;
  const int lane = tid & 63;
  const int wv = tid >> 6;
  const int wr = wv >> 1, wc = wv & 1;
  const int lr = lane & 15;
  const int lq = lane >> 4;
  const int lsw = lr & 7;

  const unsigned short* aptr[4];
  const unsigned short* bptr[4];
  #pragma unroll
  for (int i = 0; i < 4; ++i) {
    int c = i * 256 + tid;
    int row = c >> 3, kc = c & 7;
    int kcs = kc ^ (row & 7);                 // inverse-swizzled source chunk
    aptr[i] = h + (size_t)(base + row) * DFF_DIM + kcs * 8;
    bptr[i] = w2t + (size_t)(n0 + row) * (E_NUM * DFF_DIM) + e * DFF_DIM + kcs * 8;
  }

  f32x4 acc[4][4];
  #pragma unroll
  for (int m = 0; m < 4; ++m)
    #pragma unroll
    for (int n = 0; n < 4; ++n) acc[m][n] = (f32x4){0.f, 0.f, 0.f, 0.f};

  for (int k0 = 0; k0 < DFF_DIM; k0 += BK) {
    #pragma unroll
    for (int i = 0; i < 4; ++i) {
      gload_lds16(aptr[i] + k0, &As[(i * 256 + tid) * 8]);
      gload_lds16(bptr[i] + k0, &Bs[(i * 256 + tid) * 8]);
    }
    __syncthreads();
    #pragma unroll
    for (int kk = 0; kk < BK; kk += 32) {
      const int ch = (((kk >> 5) * 4 + lq) ^ lsw) * 8;
      short8_t aF[4], bF[4];
      #pragma unroll
      for (int m = 0; m < 4; ++m)
        aF[m] = *(const short8_t*)&As[(wr * 64 + m * 16 + lr) * BK + ch];
      #pragma unroll
      for (int n = 0; n < 4; ++n)
        bF[n] = *(const short8_t*)&Bs[(wc * 64 + n * 16 + lr) * BK + ch];
      #pragma unroll
      for (int m = 0; m < 4; ++m)
        #pragma unroll
        for (int n = 0; n < 4; ++n)
          acc[m][n] = __builtin_amdgcn_mfma_f32_16x16x32_bf16(aF[m], bF[n], acc[m][n], 0, 0, 0);
    }
    __syncthreads();
  }

  #pragma unroll
  for (int m = 0; m < 4; ++m) {
    #pragma unroll
    for (int j4 = 0; j4 < 4; ++j4) {
      const int p = base + wr * 64 + m * 16 + lq * 4 + j4;
      const int tok = ptok[p];
      if (tok < 0) continue;
      const float g = pgate[p];
      #pragma unroll
      for (int n = 0; n < 4; ++n) {
        const int col = n0 + wc * 64 + n * 16 + lr;
        atomicAdd(&out[(size_t)tok * D_DIM + col], g * acc[m][n][j4]);
      }
    }
  }
}

// ---------------- launch ----------------
extern "C" void kernel_launch(void* const* d_in, const int* in_sizes, int n_in,
                              void* d_out, int out_size, void* d_ws, size_t ws_size,
                              hipStream_t stream) {
  const float* x  = (const float*)d_in[0];
  const float* rw = (const float*)d_in[1];
  const float* w1 = (const float*)d_in[2];
  const float* w2 = (const float*)d_in[3];
  float* out = (float*)d_out;

  char* ws = (char*)d_ws;
  unsigned short* xb   = (unsigned short*)(ws);              // 16,777,216
  unsigned short* w1t  = (unsigned short*)(ws + 16777216);   // 33,554,432  [16384][1024]
  unsigned short* w2t  = (unsigned short*)(ws + 50331648);   // 33,554,432  [1024][16384]
  unsigned short* h    = (unsigned short*)(ws + 83886080);   // 71,303,168  [17408][2048]
  int*   ptok   = (int*)(ws + 155189248);
  float* pgate  = (float*)(ws + 155258880);
  int*   sel    = (int*)(ws + 155328512);
  float* selw   = (float*)(ws + 155394048);
  int*   counts = (int*)(ws + 155459584);
  int*   cursor = counts + 8;
  int*   padoff = counts + 16;
  int*   tiles_e = counts + 24;
  int*   tiles_b = tiles_e + MAX_TILES;
  unsigned short* zpad = (unsigned short*)(tiles_b + MAX_TILES);
  const size_t WS_NEED = 155459584 + 4096;
  if (ws_size < WS_NEED) return;

  hipMemsetAsync(out, 0, (size_t)T_TOK * D_DIM * sizeof(float), stream);
  hipMemsetAsync(counts, 0, E_NUM * sizeof(int), stream);

  tcvt_kernel<<<dim3(16384 / 32, 1024 / 32), dim3(32, 8), 0, stream>>>(w1, w1t, 1024, 16384);
  tcvt_kernel<<<dim3(1024 / 32, 16384 / 32), dim3(32, 8), 0, stream>>>(w2, w2t, 16384, 1024);
  router_kernel<<<T_TOK / 4, 256, 0, stream>>>(x, rw, sel, selw, xb);
  count_kernel<<<2 * T_TOK / 256, 256, 0, stream>>>(sel, counts);
  plan_kernel<<<1, 256, 0, stream>>>(counts, tiles_e, tiles_b, padoff, cursor, ptok, pgate, zpad);
  scatter_kernel<<<T_TOK / 256, 256, 0, stream>>>(sel, selw, padoff, cursor, ptok, pgate);
  gemm1_kernel<<<dim3(DFF_DIM / 128, MAX_TILES), 256, 0, stream>>>(xb, w1t, ptok, tiles_e,
                                                                   tiles_b, zpad, h);
  gemm2_kernel<<<dim3(D_DIM / 128, MAX_TILES), 256, 0, stream>>>(h, w2t, ptok, pgate, tiles_e,
                                                                 tiles_b, out);
}

// Round 15
// 323.035 us; speedup vs baseline: 2.3460x; 1.0086x over previous
//
#include <hip/hip_runtime.h>
#include <hip/hip_bf16.h>

// Problem constants (B=4, S=2048, D=1024, E=8, K=2, DFF=2048)
#define T_TOK 8192
#define D_DIM 1024
#define E_NUM 8
#define TOPK 2
#define DFF_DIM 2048
#define BM 128
#define BK 64
#define MAX_TILES 136                 // 17 * 8: per-XCD chunking is exactly bijective
#define MAX_PAIRS_PAD (MAX_TILES*BM)  // 17408

typedef __attribute__((ext_vector_type(8))) short short8_t;
typedef __attribute__((ext_vector_type(4))) float f32x4;

__device__ __forceinline__ unsigned short f2b(float f) {
  union { float f; unsigned u; } v; v.f = f;
  unsigned u = v.u;
  return (unsigned short)((u + 0x7fffu + ((u >> 16) & 1u)) >> 16);
}

// exact-GELU via A&S 7.1.26 erf (|err|<=1.5e-7, branchless ~15 VALU ops).
// bf16 output ulp ~0.4% >> 1.5e-7 -> numerically identical to erff path.
__device__ __forceinline__ float fast_gelu(float v) {
  float x = v * 0.70710678118654752f;
  float ax = fabsf(x);
  float t = __frcp_rn(1.f + 0.3275911f * ax);
  float poly = t * (0.254829592f + t * (-0.284496736f + t * (1.421413741f +
               t * (-1.453152027f + t * 1.061405429f))));
  float erfax = 1.f - poly * __expf(-x * x);
  float erfx = copysignf(erfax, x);
  return 0.5f * v * (1.f + erfx);
}

__device__ __forceinline__ void gload_lds16(const void* g, void* l) {
  __builtin_amdgcn_global_load_lds(
      (const __attribute__((address_space(1))) unsigned int*)g,
      (__attribute__((address_space(3))) unsigned int*)l, 16, 0, 0);
}

// src[R][C] fp32 -> dst[C][R] bf16 (tiled transpose, coalesced both sides)
__global__ void tcvt_kernel(const float* __restrict__ src, unsigned short* __restrict__ dst,
                            int R, int C) {
  __shared__ float tile[32][33];
  int c0 = blockIdx.x * 32, r0 = blockIdx.y * 32;
  int tx = threadIdx.x, ty = threadIdx.y;  // 32x8
  #pragma unroll
  for (int i = 0; i < 32; i += 8)
    tile[ty + i][tx] = src[(size_t)(r0 + ty + i) * C + c0 + tx];
  __syncthreads();
  #pragma unroll
  for (int i = 0; i < 32; i += 8)
    dst[(size_t)(c0 + ty + i) * R + r0 + tx] = f2b(tile[tx][ty + i]);
}

// ---------------- router: logits, top-2, renorm; fused x->bf16; no hot atomics
__global__ void router_kernel(const float* __restrict__ x, const float* __restrict__ rw,
                              int* __restrict__ sel, float* __restrict__ selw,
                              unsigned short* __restrict__ xb) {
  int tok = (blockIdx.x * blockDim.x + threadIdx.x) >> 6;  // one wave per token
  int lane = threadIdx.x & 63;
  if (tok >= T_TOK) return;
  const float4* xr = (const float4*)(x + (size_t)tok * D_DIM);
  ushort4* xbr = (ushort4*)(xb + (size_t)tok * D_DIM);
  float acc[E_NUM];
  #pragma unroll
  for (int e = 0; e < E_NUM; ++e) acc[e] = 0.f;
  #pragma unroll
  for (int it = 0; it < 4; ++it) {
    int i = it * 64 + lane;      // float4 index, 0..255
    float4 v = xr[i];
    ushort4 o;
    o.x = f2b(v.x); o.y = f2b(v.y); o.z = f2b(v.z); o.w = f2b(v.w);
    xbr[i] = o;                  // fused bf16 conversion of x
    const float* w = rw + (size_t)i * 4 * E_NUM;
    #pragma unroll
    for (int e = 0; e < E_NUM; ++e) acc[e] += v.x * w[e];
    #pragma unroll
    for (int e = 0; e < E_NUM; ++e) acc[e] += v.y * w[E_NUM + e];
    #pragma unroll
    for (int e = 0; e < E_NUM; ++e) acc[e] += v.z * w[2 * E_NUM + e];
    #pragma unroll
    for (int e = 0; e < E_NUM; ++e) acc[e] += v.w * w[3 * E_NUM + e];
  }
  #pragma unroll
  for (int e = 0; e < E_NUM; ++e) {
    float v = acc[e];
    #pragma unroll
    for (int off = 32; off > 0; off >>= 1) v += __shfl_xor(v, off, 64);
    acc[e] = v;
  }
  if (lane == 0) {
    float mx = acc[0];
    #pragma unroll
    for (int e = 1; e < E_NUM; ++e) mx = fmaxf(mx, acc[e]);
    float p[E_NUM];
    #pragma unroll
    for (int e = 0; e < E_NUM; ++e) p[e] = __expf(acc[e] - mx);
    int i0 = 0;
    #pragma unroll
    for (int e = 1; e < E_NUM; ++e) if (p[e] > p[i0]) i0 = e;
    int i1 = (i0 == 0) ? 1 : 0;
    #pragma unroll
    for (int e = 0; e < E_NUM; ++e) if (e != i0 && p[e] > p[i1]) i1 = e;
    float w0 = p[i0], w1 = p[i1];
    float inv = 1.f / (w0 + w1);   // softmax denominator cancels in renorm
    sel[tok * 2] = i0; selw[tok * 2] = w0 * inv;
    sel[tok * 2 + 1] = i1; selw[tok * 2 + 1] = w1 * inv;
  }
}

// ---------------- counts: LDS-aggregated histogram ----------------
__global__ void count_kernel(const int* __restrict__ sel, int* __restrict__ counts) {
  __shared__ int lc[E_NUM];
  if (threadIdx.x < E_NUM) lc[threadIdx.x] = 0;
  __syncthreads();
  int t = blockIdx.x * blockDim.x + threadIdx.x;
  if (t < 2 * T_TOK) atomicAdd(&lc[sel[t]], 1);
  __syncthreads();
  if (threadIdx.x < E_NUM) atomicAdd(&counts[threadIdx.x], lc[threadIdx.x]);
}

// ---------------- plan: padded offsets + tile table + inits ----------------
__global__ void plan_kernel(const int* __restrict__ counts, int* __restrict__ tiles_e,
                            int* __restrict__ tiles_b, int* __restrict__ pad_off,
                            int* __restrict__ cursor, int* __restrict__ ptok,
                            float* __restrict__ pgate, unsigned short* __restrict__ zpad) {
  if (threadIdx.x == 0) {
    int b = 0, t = 0;
    for (int e = 0; e < E_NUM; ++e) {
      pad_off[e] = b;
      int nt = (counts[e] + BM - 1) >> 7;
      for (int i = 0; i < nt; ++i) { tiles_e[t] = e; tiles_b[t] = b + i * BM; ++t; }
      b += nt * BM;
    }
    for (; t < MAX_TILES; ++t) { tiles_e[t] = -1; tiles_b[t] = 0; }
  }
  for (int i = threadIdx.x; i < MAX_PAIRS_PAD; i += blockDim.x) { ptok[i] = -1; pgate[i] = 0.f; }
  for (int i = threadIdx.x; i < 64; i += blockDim.x) zpad[i] = 0;
  if (threadIdx.x < E_NUM) cursor[threadIdx.x] = 0;
}

// ---------------- scatter: block-level range reservation ----------------
__global__ void scatter_kernel(const int* __restrict__ sel, const float* __restrict__ selw,
                               const int* __restrict__ pad_off, int* __restrict__ cursor,
                               int* __restrict__ ptok, float* __restrict__ pgate) {
  __shared__ int lc[E_NUM];
  __shared__ int lbase[E_NUM];
  if (threadIdx.x < E_NUM) lc[threadIdx.x] = 0;
  __syncthreads();
  int t = blockIdx.x * blockDim.x + threadIdx.x;  // one thread per token
  int e0 = sel[t * 2], e1 = sel[t * 2 + 1];
  int o0 = atomicAdd(&lc[e0], 1);
  int o1 = atomicAdd(&lc[e1], 1);
  __syncthreads();
  if (threadIdx.x < E_NUM) lbase[threadIdx.x] = atomicAdd(&cursor[threadIdx.x], lc[threadIdx.x]);
  __syncthreads();
  int s0 = pad_off[e0] + lbase[e0] + o0;
  ptok[s0] = t; pgate[s0] = selw[t * 2];
  int s1 = pad_off[e1] + lbase[e1] + o1;
  ptok[s1] = t; pgate[s1] = selw[t * 2 + 1];
}

// ======== GEMM1: r12 + fast_gelu epilogue (T1 swizzle + T2 0-conflict) ========
__global__ __launch_bounds__(256, 2) void gemm1_kernel(
    const unsigned short* __restrict__ xb, const unsigned short* __restrict__ w1t,
    const int* __restrict__ ptok, const int* __restrict__ tiles_e,
    const int* __restrict__ tiles_b, const unsigned short* __restrict__ zpad,
    unsigned short* __restrict__ h) {
  const int id = blockIdx.x + 16 * blockIdx.y;
  const int xcd = id & 7;
  const int j = id >> 3;                     // 0..271 per XCD
  const int tileIdx = xcd * 17 + (j >> 4);   // 17 tiles per XCD
  const int n0 = (j & 15) * 128;
  const int e = tiles_e[tileIdx];
  if (e < 0) return;
  const int base = tiles_b[tileIdx];

  __shared__ unsigned short As[BM * BK];
  __shared__ unsigned short Bs[BM * BK];

  const int tid = threadIdx.x;
  const int lane = tid & 63;
  const int wv = tid >> 6;
  const int wr = wv >> 1, wc = wv & 1;
  const int lr = lane & 15;
  const int lq = lane >> 4;
  const int lsw = lr & 7;                     // read-side swizzle key

  int atok[4], aoff[4];
  const unsigned short* bptr[4];
  #pragma unroll
  for (int i = 0; i < 4; ++i) {
    int c = i * 256 + tid;
    int row = c >> 3, kc = c & 7;
    int kcs = kc ^ (row & 7);                 // inverse-swizzled source chunk
    atok[i] = ptok[base + row];
    aoff[i] = kcs * 8;
    bptr[i] = w1t + (size_t)(e * DFF_DIM + n0 + row) * D_DIM + kcs * 8;
  }

  f32x4 acc[4][4];
  #pragma unroll
  for (int m = 0; m < 4; ++m)
    #pragma unroll
    for (int n = 0; n < 4; ++n) acc[m][n] = (f32x4){0.f, 0.f, 0.f, 0.f};

  for (int k0 = 0; k0 < D_DIM; k0 += BK) {
    #pragma unroll
    for (int i = 0; i < 4; ++i) {
      const unsigned short* ga =
          (atok[i] >= 0) ? (xb + (size_t)atok[i] * D_DIM + k0 + aoff[i]) : zpad;
      gload_lds16(ga, &As[(i * 256 + tid) * 8]);          // LDS dest linear
      gload_lds16(bptr[i] + k0, &Bs[(i * 256 + tid) * 8]);
    }
    __syncthreads();
    #pragma unroll
    for (int kk = 0; kk < BK; kk += 32) {
      const int ch = (((kk >> 5) * 4 + lq) ^ lsw) * 8;    // swizzled read chunk
      short8_t aF[4], bF[4];
      #pragma unroll
      for (int m = 0; m < 4; ++m)
        aF[m] = *(const short8_t*)&As[(wr * 64 + m * 16 + lr) * BK + ch];
      #pragma unroll
      for (int n = 0; n < 4; ++n)
        bF[n] = *(const short8_t*)&Bs[(wc * 64 + n * 16 + lr) * BK + ch];
      #pragma unroll
      for (int m = 0; m < 4; ++m)
        #pragma unroll
        for (int n = 0; n < 4; ++n)
          acc[m][n] = __builtin_amdgcn_mfma_f32_16x16x32_bf16(aF[m], bF[n], acc[m][n], 0, 0, 0);
    }
    __syncthreads();
  }

  #pragma unroll
  for (int m = 0; m < 4; ++m) {
    #pragma unroll
    for (int n = 0; n < 4; ++n) {
      const int col = n0 + wc * 64 + n * 16 + lr;
      #pragma unroll
      for (int j4 = 0; j4 < 4; ++j4) {
        const int row = base + wr * 64 + m * 16 + lq * 4 + j4;
        h[(size_t)row * DFF_DIM + col] = f2b(fast_gelu(acc[m][n][j4]));
      }
    }
  }
}

// ======== GEMM2: r12 unchanged (T1 swizzle + T2 0-conflict) ========
// out[tok] += gate * (h @ W2_e)
__global__ __launch_bounds__(256, 2) void gemm2_kernel(
    const unsigned short* __restrict__ h, const unsigned short* __restrict__ w2t,
    const int* __restrict__ ptok, const float* __restrict__ pgate,
    const int* __restrict__ tiles_e, const int* __restrict__ tiles_b,
    float* __restrict__ out) {
  const int id = blockIdx.x + 8 * blockIdx.y;
  const int xcd = id & 7;
  const int j = id >> 3;                     // 0..135 per XCD
  const int tileIdx = xcd * 17 + (j >> 3);   // 17 tiles per XCD
  const int n0 = (j & 7) * 128;
  const int e = tiles_e[tileIdx];
  if (e < 0) return;
  const int base = tiles_b[tileIdx];

  __shared__ unsigned short As[BM * BK];
  __shared__ unsigned short Bs[BM * BK];

  const int tid = threadIdx.x;
  const int lane = tid & 63;
  const int wv = tid >> 6;
  const int wr = wv >> 1, wc = wv & 1;
  const int lr = lane & 15;
  const int lq = lane >> 4;
  const int lsw = lr & 7;

  const unsigned short* aptr[4];
  const unsigned short* bptr[4];
  #pragma unroll
  for (int i = 0; i < 4; ++i) {
    int c = i * 256 + tid;
    int row = c >> 3, kc = c & 7;
    int kcs = kc ^ (row & 7);                 // inverse-swizzled source chunk
    aptr[i] = h + (size_t)(base + row) * DFF_DIM + kcs * 8;
    bptr[i] = w2t + (size_t)(n0 + row) * (E_NUM * DFF_DIM) + e * DFF_DIM + kcs * 8;
  }

  f32x4 acc[4][4];
  #pragma unroll
  for (int m = 0; m < 4; ++m)
    #pragma unroll
    for (int n = 0; n < 4; ++n) acc[m][n] = (f32x4){0.f, 0.f, 0.f, 0.f};

  for (int k0 = 0; k0 < DFF_DIM; k0 += BK) {
    #pragma unroll
    for (int i = 0; i < 4; ++i) {
      gload_lds16(aptr[i] + k0, &As[(i * 256 + tid) * 8]);
      gload_lds16(bptr[i] + k0, &Bs[(i * 256 + tid) * 8]);
    }
    __syncthreads();
    #pragma unroll
    for (int kk = 0; kk < BK; kk += 32) {
      const int ch = (((kk >> 5) * 4 + lq) ^ lsw) * 8;
      short8_t aF[4], bF[4];
      #pragma unroll
      for (int m = 0; m < 4; ++m)
        aF[m] = *(const short8_t*)&As[(wr * 64 + m * 16 + lr) * BK + ch];
      #pragma unroll
      for (int n = 0; n < 4; ++n)
        bF[n] = *(const short8_t*)&Bs[(wc * 64 + n * 16 + lr) * BK + ch];
      #pragma unroll
      for (int m = 0; m < 4; ++m)
        #pragma unroll
        for (int n = 0; n < 4; ++n)
          acc[m][n] = __builtin_amdgcn_mfma_f32_16x16x32_bf16(aF[m], bF[n], acc[m][n], 0, 0, 0);
    }
    __syncthreads();
  }

  #pragma unroll
  for (int m = 0; m < 4; ++m) {
    #pragma unroll
    for (int j4 = 0; j4 < 4; ++j4) {
      const int p = base + wr * 64 + m * 16 + lq * 4 + j4;
      const int tok = ptok[p];
      if (tok < 0) continue;
      const float g = pgate[p];
      #pragma unroll
      for (int n = 0; n < 4; ++n) {
        const int col = n0 + wc * 64 + n * 16 + lr;
        atomicAdd(&out[(size_t)tok * D_DIM + col], g * acc[m][n][j4]);
      }
    }
  }
}

// ---------------- launch ----------------
extern "C" void kernel_launch(void* const* d_in, const int* in_sizes, int n_in,
                              void* d_out, int out_size, void* d_ws, size_t ws_size,
                              hipStream_t stream) {
  const float* x  = (const float*)d_in[0];
  const float* rw = (const float*)d_in[1];
  const float* w1 = (const float*)d_in[2];
  const float* w2 = (const float*)d_in[3];
  float* out = (float*)d_out;

  char* ws = (char*)d_ws;
  unsigned short* xb   = (unsigned short*)(ws);              // 16,777,216
  unsigned short* w1t  = (unsigned short*)(ws + 16777216);   // 33,554,432  [16384][1024]
  unsigned short* w2t  = (unsigned short*)(ws + 50331648);   // 33,554,432  [1024][16384]
  unsigned short* h    = (unsigned short*)(ws + 83886080);   // 71,303,168  [17408][2048]
  int*   ptok   = (int*)(ws + 155189248);
  float* pgate  = (float*)(ws + 155258880);
  int*   sel    = (int*)(ws + 155328512);
  float* selw   = (float*)(ws + 155394048);
  int*   counts = (int*)(ws + 155459584);
  int*   cursor = counts + 8;
  int*   padoff = counts + 16;
  int*   tiles_e = counts + 24;
  int*   tiles_b = tiles_e + MAX_TILES;
  unsigned short* zpad = (unsigned short*)(tiles_b + MAX_TILES);
  const size_t WS_NEED = 155459584 + 4096;
  if (ws_size < WS_NEED) return;

  hipMemsetAsync(out, 0, (size_t)T_TOK * D_DIM * sizeof(float), stream);
  hipMemsetAsync(counts, 0, E_NUM * sizeof(int), stream);

  tcvt_kernel<<<dim3(16384 / 32, 1024 / 32), dim3(32, 8), 0, stream>>>(w1, w1t, 1024, 16384);
  tcvt_kernel<<<dim3(1024 / 32, 16384 / 32), dim3(32, 8), 0, stream>>>(w2, w2t, 16384, 1024);
  router_kernel<<<T_TOK / 4, 256, 0, stream>>>(x, rw, sel, selw, xb);
  count_kernel<<<2 * T_TOK / 256, 256, 0, stream>>>(sel, counts);
  plan_kernel<<<1, 256, 0, stream>>>(counts, tiles_e, tiles_b, padoff, cursor, ptok, pgate, zpad);
  scatter_kernel<<<T_TOK / 256, 256, 0, stream>>>(sel, selw, padoff, cursor, ptok, pgate);
  gemm1_kernel<<<dim3(DFF_DIM / 128, MAX_TILES), 256, 0, stream>>>(xb, w1t, ptok, tiles_e,
                                                                   tiles_b, zpad, h);
  gemm2_kernel<<<dim3(D_DIM / 128, MAX_TILES), 256, 0, stream>>>(h, w2t, ptok, pgate, tiles_e,
                                                                 tiles_b, out);
}